// Round 1
// baseline (882.377 us; speedup 1.0000x reference)
//
#include <hip/hip_runtime.h>
#include <math.h>

#define Bc 4
#define Tc 1024
#define Dc 256
#define Hc 8
#define DKc 32
#define DVc 32
#define Cc 16

// ---------------- K1: QKV projection + l2norm ----------------
// grid (512, 8, 3), block (32, 8). One output element per thread.
// blockIdx.z: 0=Q, 1=K, 2=V.  Output layout [B,H,T,32].
__global__ __launch_bounds__(256) void qkv_kernel(
    const float* __restrict__ x,
    const float* __restrict__ Wq,
    const float* __restrict__ Wk,
    const float* __restrict__ Wv,
    float* __restrict__ Q, float* __restrict__ K, float* __restrict__ V)
{
    const int tx = threadIdx.x;             // 0..31 = dk
    const int ty = threadIdx.y;             // 0..7  = row in tile
    const int row = blockIdx.x * 8 + ty;    // 0..4095 (flat b*T+t)
    const int h = blockIdx.y;
    const int mat = blockIdx.z;

    __shared__ __align__(16) float xs[8][Dc];
    {
        const float* xr = x + (size_t)row * Dc;
#pragma unroll
        for (int p = 0; p < 2; ++p) {
            int col = tx * 4 + p * 128;
            *(float4*)(&xs[ty][col]) = *(const float4*)(xr + col);
        }
    }
    __syncthreads();

    const float* Wsel = (mat == 0) ? Wq : (mat == 1) ? Wk : Wv;
    const float* wr = Wsel + ((size_t)h * DKc + tx) * Dc;
    float acc = 0.f;
#pragma unroll 4
    for (int d = 0; d < Dc; d += 4) {
        float4 wv = *(const float4*)(wr + d);
        float4 xv = *(const float4*)(&xs[ty][d]);
        acc = fmaf(wv.x, xv.x, acc);
        acc = fmaf(wv.y, xv.y, acc);
        acc = fmaf(wv.z, xv.z, acc);
        acc = fmaf(wv.w, xv.w, acc);
    }
    float val = acc;
    if (mat < 2) {
        // l2 normalize across the 32 dk lanes (xor masks stay inside tx group)
        float s2 = val * val;
#pragma unroll
        for (int m = 16; m >= 1; m >>= 1) s2 += __shfl_xor(s2, m, 64);
        float n = sqrtf(s2);
        val = val / fmaxf(n, 1e-12f);
    }
    float* Out = (mat == 0) ? Q : (mat == 1) ? K : V;
    const int b = row >> 10;
    const int t = row & 1023;
    Out[(((size_t)b * Hc + h) * Tc + t) * DKc + tx] = val;
}

// ---------------- K2: fused attention (flash-style, no S materialization) ----
#define TT 64   // t rows per block
#define ST 64   // s chunk
#define KS 36   // padded LDS stride for k/v tiles (16B aligned, banks split by s-phase)
#define DS 68   // padded LDS stride for d tile

__global__ __launch_bounds__(256) void attn_kernel(
    const float* __restrict__ Q, const float* __restrict__ K,
    const float* __restrict__ V,
    const float* __restrict__ rel, const int* __restrict__ msk,
    const float* __restrict__ pw1, const float* __restrict__ pb1,
    const float* __restrict__ pw2, const float* __restrict__ pb2,
    float* __restrict__ Y)
{
    const int tid = threadIdx.x;
    const int r = tid >> 2;     // 0..63 row in tile
    const int c = tid & 3;      // s-phase
    const int bh = blockIdx.y;  // b*H + h
    const int b = bh >> 3, h = bh & 7;
    const int t = blockIdx.x * TT + r;

    // pos-bias reparameterization: bias(d) = pB + pA*d + sum_c wc|d - rc|
    // (lrelu(x) = 0.505x + 0.495|x|)
    float pA = 0.f, pB = pb2[h];
    float wc[Cc], rc[Cc];
#pragma unroll
    for (int i = 0; i < Cc; ++i) {
        float w1 = pw1[h * Cc + i];
        float b1 = pb1[h * Cc + i];
        float w2 = pw2[h * Cc + i];
        if (w1 != 0.f) {
            pA = fmaf(0.505f * w2, w1, pA);
            pB = fmaf(0.505f * w2, b1, pB);
            wc[i] = 0.495f * w2 * fabsf(w1);
            rc[i] = -b1 / w1;
        } else {
            pB += w2 * (b1 >= 0.f ? b1 : 0.01f * b1);
            wc[i] = 0.f;
            rc[i] = 0.f;
        }
    }

    float q[DKc];
    {
        const float* qr = Q + ((size_t)bh * Tc + t) * DKc;
#pragma unroll
        for (int i = 0; i < DKc; i += 4) {
            float4 v4 = *(const float4*)(qr + i);
            q[i] = v4.x; q[i + 1] = v4.y; q[i + 2] = v4.z; q[i + 3] = v4.w;
        }
    }

    float acc[DVc];
#pragma unroll
    for (int i = 0; i < DVc; ++i) acc[i] = 0.f;
    float ssum = 0.f;

    __shared__ __align__(16) float ks[ST][KS];
    __shared__ __align__(16) float vs[ST][KS];
    __shared__ __align__(16) float dm[TT][DS];

    const size_t kvbase = (size_t)bh * Tc * DKc;
    const float* drow = rel + ((size_t)b * Tc + t) * Tc;
    const int* mrow = msk + ((size_t)b * Tc + t) * Tc;

    for (int s0 = 0; s0 < Tc; s0 += ST) {
        // stage K,V chunk: 64 s-rows x 32, coalesced float4
        {
            const int sr = tid >> 2;
            const int c8 = (tid & 3) * 8;
            const float* kg = K + kvbase + (size_t)(s0 + sr) * DKc + c8;
            const float* vg = V + kvbase + (size_t)(s0 + sr) * DKc + c8;
            float4 k0 = *(const float4*)(kg);
            float4 k1 = *(const float4*)(kg + 4);
            float4 v0 = *(const float4*)(vg);
            float4 v1 = *(const float4*)(vg + 4);
            *(float4*)(&ks[sr][c8])     = k0;
            *(float4*)(&ks[sr][c8 + 4]) = k1;
            *(float4*)(&vs[sr][c8])     = v0;
            *(float4*)(&vs[sr][c8 + 4]) = v1;
        }
        // stage d + mask combined: masked -> -1 sentinel (d >= 0 always)
        {
            const int scb = c * 16;
#pragma unroll
            for (int p = 0; p < 4; ++p) {
                float4 dv = *(const float4*)(drow + s0 + scb + p * 4);
                int4  mv = *(const int4*)(mrow + s0 + scb + p * 4);
                float4 o;
                o.x = mv.x ? -1.f : dv.x;
                o.y = mv.y ? -1.f : dv.y;
                o.z = mv.z ? -1.f : dv.z;
                o.w = mv.w ? -1.f : dv.w;
                *(float4*)(&dm[r][scb + p * 4]) = o;
            }
        }
        __syncthreads();

#pragma unroll 4
        for (int j = 0; j < 16; ++j) {
            const int sl = j * 4 + c;   // 4 phase-lanes hit disjoint banks
            float dval = dm[r][sl];
            float dot = 0.f;
#pragma unroll
            for (int i = 0; i < DKc; i += 4) {
                float4 kv = *(const float4*)(&ks[sl][i]);
                dot = fmaf(q[i],     kv.x, dot);
                dot = fmaf(q[i + 1], kv.y, dot);
                dot = fmaf(q[i + 2], kv.z, dot);
                dot = fmaf(q[i + 3], kv.w, dot);
            }
            float bias = fmaf(pA, dval, pB);
#pragma unroll
            for (int i = 0; i < Cc; ++i)
                bias = fmaf(wc[i], fabsf(dval - rc[i]), bias);
            float logit = (dval < 0.f) ? -1e30f : (dot - bias);
            float z = __expf(logit);   // exp(-1e30) == 0, matches exp(NEG)
            ssum += z;
#pragma unroll
            for (int i = 0; i < DVc; i += 4) {
                float4 vv = *(const float4*)(&vs[sl][i]);
                acc[i]     = fmaf(z, vv.x, acc[i]);
                acc[i + 1] = fmaf(z, vv.y, acc[i + 1]);
                acc[i + 2] = fmaf(z, vv.z, acc[i + 2]);
                acc[i + 3] = fmaf(z, vv.w, acc[i + 3]);
            }
        }
        __syncthreads();
    }

    // combine the 4 s-phase partials per row: phases are 4 consecutive lanes
#pragma unroll
    for (int i = 0; i < DVc; ++i) {
        acc[i] += __shfl_xor(acc[i], 1, 64);
        acc[i] += __shfl_xor(acc[i], 2, 64);
    }
    ssum += __shfl_xor(ssum, 1, 64);
    ssum += __shfl_xor(ssum, 2, 64);
    const float scale = 1.f / (ssum + 1e-5f);

    float* yr = Y + ((size_t)b * Tc + t) * Dc + h * DVc;
#define STORE_SLICE(base) do { \
        float4 a0; a0.x = acc[(base)+0]*scale; a0.y = acc[(base)+1]*scale; \
        a0.z = acc[(base)+2]*scale; a0.w = acc[(base)+3]*scale; \
        float4 a1; a1.x = acc[(base)+4]*scale; a1.y = acc[(base)+5]*scale; \
        a1.z = acc[(base)+6]*scale; a1.w = acc[(base)+7]*scale; \
        *(float4*)(yr + (base)) = a0; *(float4*)(yr + (base) + 4) = a1; \
    } while (0)
    if (c == 0)      STORE_SLICE(0);
    else if (c == 1) STORE_SLICE(8);
    else if (c == 2) STORE_SLICE(16);
    else             STORE_SLICE(24);
#undef STORE_SLICE
}

// ---------------- K3/K4: GEMM[4096,256,256] + bias (+lrelu) + residual + LN --
__global__ __launch_bounds__(256) void proj_ln_kernel(
    const float* __restrict__ inp,
    const float* __restrict__ res,
    const float* __restrict__ W,
    const float* __restrict__ bias,
    const float* __restrict__ g,
    const float* __restrict__ beta,
    float* __restrict__ out,
    int do_lrelu)
{
    const int j = threadIdx.x;
    const int row = blockIdx.x;
    __shared__ __align__(16) float xs[Dc];
    __shared__ float red[8];
    xs[j] = inp[(size_t)row * Dc + j];
    __syncthreads();
    const float* wr = W + (size_t)j * Dc;
    float acc = 0.f;
#pragma unroll 4
    for (int d = 0; d < Dc; d += 4) {
        float4 wv = *(const float4*)(wr + d);
        float4 xv = *(const float4*)(&xs[d]);
        acc = fmaf(wv.x, xv.x, acc);
        acc = fmaf(wv.y, xv.y, acc);
        acc = fmaf(wv.z, xv.z, acc);
        acc = fmaf(wv.w, xv.w, acc);
    }
    float yv = acc + bias[j];
    if (do_lrelu) yv = (yv >= 0.f) ? yv : 0.01f * yv;
    float s = res[(size_t)row * Dc + j] + yv;

    float s1 = s, s2 = s * s;
#pragma unroll
    for (int m = 32; m >= 1; m >>= 1) {
        s1 += __shfl_xor(s1, m, 64);
        s2 += __shfl_xor(s2, m, 64);
    }
    const int w = j >> 6;
    if ((j & 63) == 0) { red[w] = s1; red[w + 4] = s2; }
    __syncthreads();
    float S1 = red[0] + red[1] + red[2] + red[3];
    float S2 = red[4] + red[5] + red[6] + red[7];
    float mu = S1 * (1.f / Dc);
    float var = S2 * (1.f / Dc) - mu * mu;
    float o = (s - mu) * rsqrtf(var + 1e-5f) * g[j] + beta[j];
    out[(size_t)row * Dc + j] = o;
}

extern "C" void kernel_launch(void* const* d_in, const int* in_sizes, int n_in,
                              void* d_out, int out_size, void* d_ws, size_t ws_size,
                              hipStream_t stream) {
    const float* x    = (const float*)d_in[0];
    const int*   mask = (const int*)d_in[1];
    const float* rel  = (const float*)d_in[2];   // [B,1,T,T] == flat [B,T,T]
    const float* Wq   = (const float*)d_in[3];
    const float* Wk   = (const float*)d_in[4];
    const float* Wv   = (const float*)d_in[5];
    const float* pw1  = (const float*)d_in[6];
    const float* pb1  = (const float*)d_in[7];
    const float* pw2  = (const float*)d_in[8];
    const float* pb2  = (const float*)d_in[9];
    const float* Wo   = (const float*)d_in[10];
    const float* bo   = (const float*)d_in[11];
    const float* Wf   = (const float*)d_in[12];
    const float* bf   = (const float*)d_in[13];
    const float* g1   = (const float*)d_in[14];
    const float* be1  = (const float*)d_in[15];
    const float* g2   = (const float*)d_in[16];
    const float* be2  = (const float*)d_in[17];
    float* out = (float*)d_out;

    float* ws = (float*)d_ws;
    const size_t N1 = (size_t)Bc * Hc * Tc * DKc;  // 1,048,576
    float* Q  = ws;
    float* K  = ws + N1;
    float* V  = ws + 2 * N1;
    float* Y  = ws + 3 * N1;   // heads concat, [B,T,D]
    float* ZZ = ws + 4 * N1;   // LN1 output,   [B,T,D]

    qkv_kernel<<<dim3(Bc * Tc / 8, Hc, 3), dim3(32, 8), 0, stream>>>(
        x, Wq, Wk, Wv, Q, K, V);
    attn_kernel<<<dim3(Tc / TT, Bc * Hc), 256, 0, stream>>>(
        Q, K, V, rel, mask, pw1, pb1, pw2, pb2, Y);
    proj_ln_kernel<<<Bc * Tc, Dc, 0, stream>>>(Y, x,  Wo, bo, g1, be1, ZZ, 0);
    proj_ln_kernel<<<Bc * Tc, Dc, 0, stream>>>(ZZ, ZZ, Wf, bf, g2, be2, out, 1);
}

// Round 2
// 372.725 us; speedup vs baseline: 2.3674x; 2.3674x over previous
//
#include <hip/hip_runtime.h>
#include <math.h>

#define Bc 4
#define Tc 1024
#define Dc 256
#define Hc 8
#define DKc 32
#define DVc 32
#define Cc 16
#define LUTN 1024

// ---------------- K0: build per-head PWL LUT for pos-bias -------------------
// bias(h,d) = pb2[h] + sum_c pw2[h,c]*lrelu(pw1[h,c]*d + pb1[h,c]); d in [0,1)
// LUT[h][i] = (a,b) with bias ~= a*d + b on bin [i/1024,(i+1)/1024)
__global__ __launch_bounds__(256) void lut_build(
    const float* __restrict__ pw1, const float* __restrict__ pb1,
    const float* __restrict__ pw2, const float* __restrict__ pb2,
    float2* __restrict__ LUT)
{
    const int h = blockIdx.x;
    float w1[Cc], b1[Cc], w2[Cc];
#pragma unroll
    for (int c = 0; c < Cc; ++c) {
        w1[c] = pw1[h * Cc + c];
        b1[c] = pb1[h * Cc + c];
        w2[c] = pw2[h * Cc + c];
    }
    const float p2 = pb2[h];
    for (int bin = threadIdx.x; bin < LUTN; bin += blockDim.x) {
        float d0 = bin * (1.f / LUTN);
        float d1 = (bin + 1) * (1.f / LUTN);
        float y0 = p2, y1 = p2;
#pragma unroll
        for (int c = 0; c < Cc; ++c) {
            float h0 = fmaf(w1[c], d0, b1[c]);
            float h1 = fmaf(w1[c], d1, b1[c]);
            y0 = fmaf(w2[c], (h0 >= 0.f ? h0 : 0.01f * h0), y0);
            y1 = fmaf(w2[c], (h1 >= 0.f ? h1 : 0.01f * h1), y1);
        }
        float a = (y1 - y0) * (float)LUTN;
        float b = y0 - a * d0;
        LUT[h * LUTN + bin] = make_float2(a, b);
    }
}

// ---------------- tiled fp32 GEMM: out[4096 x N] = x[4096 x 256] . W^T ------
#define BM 64
#define BN 64
#define BK 64
#define LS 68   // LDS stride (floats); 272B rows keep float4 alignment

// K1: QKV fused GEMM. grid (64, 12): blockIdx.y -> (mat, 64-feat slice).
// Output layout [B,H,T,32] per mat, NO normalization (done in attn).
__global__ __launch_bounds__(256) void gemm_qkv(
    const float* __restrict__ x,
    const float* __restrict__ Wq, const float* __restrict__ Wk,
    const float* __restrict__ Wv,
    float* __restrict__ Q, float* __restrict__ K, float* __restrict__ V)
{
    const int tid = threadIdx.x;
    const int tr = tid >> 4;          // 0..15 -> rows tr*4..tr*4+3
    const int tc = tid & 15;          // 0..15 -> feats tc*4..tc*4+3
    const int rbase = blockIdx.x * BM;
    const int ft = blockIdx.y;
    const int mat = ft >> 2;
    const int fb = (ft & 3) * BN;     // feature offset within the mat (0..192)

    const float* Wsel = (mat == 0) ? Wq : (mat == 1) ? Wk : Wv;

    __shared__ __align__(16) float As[BK][LS];
    __shared__ __align__(16) float Ws[BK][LS];

    float acc[4][4];
#pragma unroll
    for (int i = 0; i < 4; ++i)
#pragma unroll
        for (int j = 0; j < 4; ++j) acc[i][j] = 0.f;

    const int lr = tid >> 2;          // 0..63
    const int lk = (tid & 3) << 4;    // 0,16,32,48

    for (int k0 = 0; k0 < Dc; k0 += BK) {
        const float* ag = x + (size_t)(rbase + lr) * Dc + k0 + lk;
        const float* wg = Wsel + (size_t)(fb + lr) * Dc + k0 + lk;
#pragma unroll
        for (int j = 0; j < 4; ++j) {
            float4 a4 = *(const float4*)(ag + 4 * j);
            float4 w4 = *(const float4*)(wg + 4 * j);
            const int kk = lk + 4 * j;
            As[kk + 0][lr] = a4.x; As[kk + 1][lr] = a4.y;
            As[kk + 2][lr] = a4.z; As[kk + 3][lr] = a4.w;
            Ws[kk + 0][lr] = w4.x; Ws[kk + 1][lr] = w4.y;
            Ws[kk + 2][lr] = w4.z; Ws[kk + 3][lr] = w4.w;
        }
        __syncthreads();
#pragma unroll 4
        for (int k = 0; k < BK; ++k) {
            float4 a4 = *(const float4*)&As[k][tr * 4];
            float4 w4 = *(const float4*)&Ws[k][tc * 4];
            acc[0][0] = fmaf(a4.x, w4.x, acc[0][0]);
            acc[0][1] = fmaf(a4.x, w4.y, acc[0][1]);
            acc[0][2] = fmaf(a4.x, w4.z, acc[0][2]);
            acc[0][3] = fmaf(a4.x, w4.w, acc[0][3]);
            acc[1][0] = fmaf(a4.y, w4.x, acc[1][0]);
            acc[1][1] = fmaf(a4.y, w4.y, acc[1][1]);
            acc[1][2] = fmaf(a4.y, w4.z, acc[1][2]);
            acc[1][3] = fmaf(a4.y, w4.w, acc[1][3]);
            acc[2][0] = fmaf(a4.z, w4.x, acc[2][0]);
            acc[2][1] = fmaf(a4.z, w4.y, acc[2][1]);
            acc[2][2] = fmaf(a4.z, w4.z, acc[2][2]);
            acc[2][3] = fmaf(a4.z, w4.w, acc[2][3]);
            acc[3][0] = fmaf(a4.w, w4.x, acc[3][0]);
            acc[3][1] = fmaf(a4.w, w4.y, acc[3][1]);
            acc[3][2] = fmaf(a4.w, w4.z, acc[3][2]);
            acc[3][3] = fmaf(a4.w, w4.w, acc[3][3]);
        }
        __syncthreads();
    }

    float* Out = (mat == 0) ? Q : (mat == 1) ? K : V;
    const int flocal = fb + tc * 4;
    const int h = flocal >> 5;
    const int dk = flocal & 31;
#pragma unroll
    for (int i = 0; i < 4; ++i) {
        const int row = rbase + tr * 4 + i;
        const int b = row >> 10, t = row & 1023;
        float4 o; o.x = acc[i][0]; o.y = acc[i][1]; o.z = acc[i][2]; o.w = acc[i][3];
        *(float4*)(Out + (((size_t)b * Hc + h) * Tc + t) * DKc + dk) = o;
    }
}

// K3/K5: GEMM + bias (+optional lrelu), out row-major [4096][256].
__global__ __launch_bounds__(256) void gemm_bias(
    const float* __restrict__ A, const float* __restrict__ W,
    const float* __restrict__ bias, float* __restrict__ out, int do_lrelu)
{
    const int tid = threadIdx.x;
    const int tr = tid >> 4;
    const int tc = tid & 15;
    const int rbase = blockIdx.x * BM;
    const int fb = blockIdx.y * BN;

    __shared__ __align__(16) float As[BK][LS];
    __shared__ __align__(16) float Ws[BK][LS];

    float acc[4][4];
#pragma unroll
    for (int i = 0; i < 4; ++i)
#pragma unroll
        for (int j = 0; j < 4; ++j) acc[i][j] = 0.f;

    const int lr = tid >> 2;
    const int lk = (tid & 3) << 4;

    for (int k0 = 0; k0 < Dc; k0 += BK) {
        const float* ag = A + (size_t)(rbase + lr) * Dc + k0 + lk;
        const float* wg = W + (size_t)(fb + lr) * Dc + k0 + lk;
#pragma unroll
        for (int j = 0; j < 4; ++j) {
            float4 a4 = *(const float4*)(ag + 4 * j);
            float4 w4 = *(const float4*)(wg + 4 * j);
            const int kk = lk + 4 * j;
            As[kk + 0][lr] = a4.x; As[kk + 1][lr] = a4.y;
            As[kk + 2][lr] = a4.z; As[kk + 3][lr] = a4.w;
            Ws[kk + 0][lr] = w4.x; Ws[kk + 1][lr] = w4.y;
            Ws[kk + 2][lr] = w4.z; Ws[kk + 3][lr] = w4.w;
        }
        __syncthreads();
#pragma unroll 4
        for (int k = 0; k < BK; ++k) {
            float4 a4 = *(const float4*)&As[k][tr * 4];
            float4 w4 = *(const float4*)&Ws[k][tc * 4];
            acc[0][0] = fmaf(a4.x, w4.x, acc[0][0]);
            acc[0][1] = fmaf(a4.x, w4.y, acc[0][1]);
            acc[0][2] = fmaf(a4.x, w4.z, acc[0][2]);
            acc[0][3] = fmaf(a4.x, w4.w, acc[0][3]);
            acc[1][0] = fmaf(a4.y, w4.x, acc[1][0]);
            acc[1][1] = fmaf(a4.y, w4.y, acc[1][1]);
            acc[1][2] = fmaf(a4.y, w4.z, acc[1][2]);
            acc[1][3] = fmaf(a4.y, w4.w, acc[1][3]);
            acc[2][0] = fmaf(a4.z, w4.x, acc[2][0]);
            acc[2][1] = fmaf(a4.z, w4.y, acc[2][1]);
            acc[2][2] = fmaf(a4.z, w4.z, acc[2][2]);
            acc[2][3] = fmaf(a4.z, w4.w, acc[2][3]);
            acc[3][0] = fmaf(a4.w, w4.x, acc[3][0]);
            acc[3][1] = fmaf(a4.w, w4.y, acc[3][1]);
            acc[3][2] = fmaf(a4.w, w4.z, acc[3][2]);
            acc[3][3] = fmaf(a4.w, w4.w, acc[3][3]);
        }
        __syncthreads();
    }

    const int fcol = fb + tc * 4;
    float4 bv = *(const float4*)(bias + fcol);
#pragma unroll
    for (int i = 0; i < 4; ++i) {
        const int row = rbase + tr * 4 + i;
        float4 o;
        o.x = acc[i][0] + bv.x; o.y = acc[i][1] + bv.y;
        o.z = acc[i][2] + bv.z; o.w = acc[i][3] + bv.w;
        if (do_lrelu) {
            o.x = o.x >= 0.f ? o.x : 0.01f * o.x;
            o.y = o.y >= 0.f ? o.y : 0.01f * o.y;
            o.z = o.z >= 0.f ? o.z : 0.01f * o.z;
            o.w = o.w >= 0.f ? o.w : 0.01f * o.w;
        }
        *(float4*)(out + (size_t)row * Dc + fcol) = o;
    }
}

// ---------------- K2: fused attention -------------------
#define TT 64
#define ST 64
#define KS 36
#define DS 68

__global__ __launch_bounds__(256) void attn_kernel(
    const float* __restrict__ Q, const float* __restrict__ K,
    const float* __restrict__ V,
    const float* __restrict__ rel, const int* __restrict__ msk,
    const float2* __restrict__ LUT,
    float* __restrict__ Y)
{
    const int tid = threadIdx.x;
    const int r = tid >> 2;     // row in tile
    const int c = tid & 3;      // s-phase
    const int bh = blockIdx.y;
    const int b = bh >> 3, h = bh & 7;
    const int t = blockIdx.x * TT + r;

    __shared__ __align__(16) float ks[ST][KS];
    __shared__ __align__(16) float vs[ST][KS];
    __shared__ __align__(16) float dm[TT][DS];
    __shared__ __align__(16) float2 lut[LUTN];

    // stage this head's LUT
    {
        const float2* src = LUT + h * LUTN;
#pragma unroll
        for (int p = 0; p < 4; ++p) lut[tid + p * 256] = src[tid + p * 256];
    }

    // load + self-normalize q row
    float q[DKc];
    {
        const float* qr = Q + ((size_t)bh * Tc + t) * DKc;
        float ss = 0.f;
#pragma unroll
        for (int i = 0; i < DKc; i += 4) {
            float4 v4 = *(const float4*)(qr + i);
            q[i] = v4.x; q[i + 1] = v4.y; q[i + 2] = v4.z; q[i + 3] = v4.w;
            ss = fmaf(v4.x, v4.x, ss); ss = fmaf(v4.y, v4.y, ss);
            ss = fmaf(v4.z, v4.z, ss); ss = fmaf(v4.w, v4.w, ss);
        }
        float sc = 1.f / fmaxf(sqrtf(ss), 1e-12f);
#pragma unroll
        for (int i = 0; i < DKc; ++i) q[i] *= sc;
    }

    float acc[DVc];
#pragma unroll
    for (int i = 0; i < DVc; ++i) acc[i] = 0.f;
    float ssum = 0.f;

    const size_t kvbase = (size_t)bh * Tc * DKc;
    const float* drow = rel + ((size_t)b * Tc + t) * Tc;
    const int* mrow = msk + ((size_t)b * Tc + t) * Tc;

    __syncthreads();   // lut staged

    for (int s0 = 0; s0 < Tc; s0 += ST) {
        // stage K (normalized) and V
        {
            const int sr = tid >> 2;
            const int c8 = (tid & 3) * 8;
            const float* kg = K + kvbase + (size_t)(s0 + sr) * DKc + c8;
            const float* vg = V + kvbase + (size_t)(s0 + sr) * DKc + c8;
            float4 k0 = *(const float4*)(kg);
            float4 k1 = *(const float4*)(kg + 4);
            float4 v0 = *(const float4*)(vg);
            float4 v1 = *(const float4*)(vg + 4);
            float ssq = k0.x * k0.x + k0.y * k0.y + k0.z * k0.z + k0.w * k0.w
                      + k1.x * k1.x + k1.y * k1.y + k1.z * k1.z + k1.w * k1.w;
            ssq += __shfl_xor(ssq, 1, 64);
            ssq += __shfl_xor(ssq, 2, 64);
            float sc = 1.f / fmaxf(sqrtf(ssq), 1e-12f);
            k0.x *= sc; k0.y *= sc; k0.z *= sc; k0.w *= sc;
            k1.x *= sc; k1.y *= sc; k1.z *= sc; k1.w *= sc;
            *(float4*)(&ks[sr][c8])     = k0;
            *(float4*)(&ks[sr][c8 + 4]) = k1;
            *(float4*)(&vs[sr][c8])     = v0;
            *(float4*)(&vs[sr][c8 + 4]) = v1;
        }
        // stage d with mask sentinel
        {
            const int scb = c * 16;
#pragma unroll
            for (int p = 0; p < 4; ++p) {
                float4 dv = *(const float4*)(drow + s0 + scb + p * 4);
                int4  mv = *(const int4*)(mrow + s0 + scb + p * 4);
                float4 o;
                o.x = mv.x ? -1.f : dv.x;
                o.y = mv.y ? -1.f : dv.y;
                o.z = mv.z ? -1.f : dv.z;
                o.w = mv.w ? -1.f : dv.w;
                *(float4*)(&dm[r][scb + p * 4]) = o;
            }
        }
        __syncthreads();

#pragma unroll 4
        for (int j = 0; j < 16; ++j) {
            const int sl = j * 4 + c;
            float dval = dm[r][sl];
            int bin = (int)(dval * (float)LUTN);
            bin = bin < 0 ? 0 : (bin > LUTN - 1 ? LUTN - 1 : bin);
            float2 ab = lut[bin];
            float dot0 = 0.f, dot1 = 0.f;
#pragma unroll
            for (int i = 0; i < 16; i += 4) {
                float4 kv = *(const float4*)(&ks[sl][i]);
                dot0 = fmaf(q[i],     kv.x, dot0);
                dot0 = fmaf(q[i + 1], kv.y, dot0);
                dot0 = fmaf(q[i + 2], kv.z, dot0);
                dot0 = fmaf(q[i + 3], kv.w, dot0);
            }
#pragma unroll
            for (int i = 16; i < 32; i += 4) {
                float4 kv = *(const float4*)(&ks[sl][i]);
                dot1 = fmaf(q[i],     kv.x, dot1);
                dot1 = fmaf(q[i + 1], kv.y, dot1);
                dot1 = fmaf(q[i + 2], kv.z, dot1);
                dot1 = fmaf(q[i + 3], kv.w, dot1);
            }
            float bias = fmaf(ab.x, dval, ab.y);
            float logit = (dval < 0.f) ? -1e30f : (dot0 + dot1 - bias);
            float z = __expf(logit);
            ssum += z;
#pragma unroll
            for (int i = 0; i < DVc; i += 4) {
                float4 vv = *(const float4*)(&vs[sl][i]);
                acc[i]     = fmaf(z, vv.x, acc[i]);
                acc[i + 1] = fmaf(z, vv.y, acc[i + 1]);
                acc[i + 2] = fmaf(z, vv.z, acc[i + 2]);
                acc[i + 3] = fmaf(z, vv.w, acc[i + 3]);
            }
        }
        __syncthreads();
    }

#pragma unroll
    for (int i = 0; i < DVc; ++i) {
        acc[i] += __shfl_xor(acc[i], 1, 64);
        acc[i] += __shfl_xor(acc[i], 2, 64);
    }
    ssum += __shfl_xor(ssum, 1, 64);
    ssum += __shfl_xor(ssum, 2, 64);
    const float scale = 1.f / (ssum + 1e-5f);

    float* yr = Y + ((size_t)b * Tc + t) * Dc + h * DVc;
#define STORE_SLICE(base) do { \
        float4 a0; a0.x = acc[(base)+0]*scale; a0.y = acc[(base)+1]*scale; \
        a0.z = acc[(base)+2]*scale; a0.w = acc[(base)+3]*scale; \
        float4 a1; a1.x = acc[(base)+4]*scale; a1.y = acc[(base)+5]*scale; \
        a1.z = acc[(base)+6]*scale; a1.w = acc[(base)+7]*scale; \
        *(float4*)(yr + (base)) = a0; *(float4*)(yr + (base) + 4) = a1; \
    } while (0)
    if (c == 0)      STORE_SLICE(0);
    else if (c == 1) STORE_SLICE(8);
    else if (c == 2) STORE_SLICE(16);
    else             STORE_SLICE(24);
#undef STORE_SLICE
}

// ---------------- K4/K6: residual + LayerNorm -------------------
__global__ __launch_bounds__(256) void resid_ln_kernel(
    const float* __restrict__ y, const float* __restrict__ res,
    const float* __restrict__ g, const float* __restrict__ beta,
    float* __restrict__ out)
{
    const int j = threadIdx.x;
    const int row = blockIdx.x;
    __shared__ float red[8];
    float s = y[(size_t)row * Dc + j] + res[(size_t)row * Dc + j];

    float s1 = s, s2 = s * s;
#pragma unroll
    for (int m = 32; m >= 1; m >>= 1) {
        s1 += __shfl_xor(s1, m, 64);
        s2 += __shfl_xor(s2, m, 64);
    }
    const int w = j >> 6;
    if ((j & 63) == 0) { red[w] = s1; red[w + 4] = s2; }
    __syncthreads();
    float S1 = red[0] + red[1] + red[2] + red[3];
    float S2 = red[4] + red[5] + red[6] + red[7];
    float mu = S1 * (1.f / Dc);
    float var = S2 * (1.f / Dc) - mu * mu;
    float o = (s - mu) * rsqrtf(var + 1e-5f) * g[j] + beta[j];
    out[(size_t)row * Dc + j] = o;
}

extern "C" void kernel_launch(void* const* d_in, const int* in_sizes, int n_in,
                              void* d_out, int out_size, void* d_ws, size_t ws_size,
                              hipStream_t stream) {
    const float* x    = (const float*)d_in[0];
    const int*   mask = (const int*)d_in[1];
    const float* rel  = (const float*)d_in[2];
    const float* Wq   = (const float*)d_in[3];
    const float* Wk   = (const float*)d_in[4];
    const float* Wv   = (const float*)d_in[5];
    const float* pw1  = (const float*)d_in[6];
    const float* pb1  = (const float*)d_in[7];
    const float* pw2  = (const float*)d_in[8];
    const float* pb2  = (const float*)d_in[9];
    const float* Wo   = (const float*)d_in[10];
    const float* bo   = (const float*)d_in[11];
    const float* Wf   = (const float*)d_in[12];
    const float* bf   = (const float*)d_in[13];
    const float* g1   = (const float*)d_in[14];
    const float* be1  = (const float*)d_in[15];
    const float* g2   = (const float*)d_in[16];
    const float* be2  = (const float*)d_in[17];
    float* out = (float*)d_out;

    float* ws = (float*)d_ws;
    const size_t N1 = (size_t)Bc * Hc * Tc * DKc;  // 1,048,576 floats = 4 MB
    float* Q  = ws;              // raw q
    float* K  = ws + N1;         // raw k
    float* V  = ws + 2 * N1;     // v
    float* Y  = ws + 3 * N1;     // attn heads concat [B,T,D]
    float2* LUT = (float2*)(ws + 4 * N1);  // 8 x 1024 float2
    // buffer reuse after attention:
    float* PY = Q;   // Wo-proj output
    float* ZZ = K;   // LN1 output
    float* FY = V;   // FFN (lrelu) output

    lut_build<<<Hc, 256, 0, stream>>>(pw1, pb1, pw2, pb2, LUT);
    gemm_qkv<<<dim3(Bc * Tc / BM, 12), 256, 0, stream>>>(x, Wq, Wk, Wv, Q, K, V);
    attn_kernel<<<dim3(Tc / TT, Bc * Hc), 256, 0, stream>>>(
        Q, K, V, rel, mask, LUT, Y);
    gemm_bias<<<dim3(Bc * Tc / BM, Dc / BN), 256, 0, stream>>>(Y, Wo, bo, PY, 0);
    resid_ln_kernel<<<Bc * Tc, Dc, 0, stream>>>(PY, x, g1, be1, ZZ);
    gemm_bias<<<dim3(Bc * Tc / BM, Dc / BN), 256, 0, stream>>>(ZZ, Wf, bf, FY, 1);
    resid_ln_kernel<<<Bc * Tc, Dc, 0, stream>>>(FY, ZZ, g2, be2, out);
}

// Round 3
// 220.670 us; speedup vs baseline: 3.9986x; 1.6891x over previous
//
#include <hip/hip_runtime.h>
#include <math.h>

#define Bc 4
#define Tc 1024
#define Dc 256
#define Hc 8
#define Cc 16
#define LUTN 256

typedef __attribute__((ext_vector_type(8))) short short8;
typedef __attribute__((ext_vector_type(4))) float f32x4;

__device__ __forceinline__ unsigned bf16u(float x) {
    unsigned u = __float_as_uint(x);
    return (u + 0x7FFFu + ((u >> 16) & 1u)) >> 16;
}
__device__ __forceinline__ unsigned pk2(float lo, float hi) {
    return bf16u(lo) | (bf16u(hi) << 16);
}

// ---------------- K0: per-head PWL LUT for pos-bias, layout [bin][head] -----
__global__ __launch_bounds__(256) void lut_build(
    const float* __restrict__ pw1, const float* __restrict__ pb1,
    const float* __restrict__ pw2, const float* __restrict__ pb2,
    float2* __restrict__ LUT)
{
    const int bin = threadIdx.x;
    const float d0 = bin * (1.f / LUTN), d1 = (bin + 1) * (1.f / LUTN);
    for (int h = 0; h < Hc; ++h) {
        float y0 = pb2[h], y1 = pb2[h];
#pragma unroll
        for (int c = 0; c < Cc; ++c) {
            float w1 = pw1[h * Cc + c], b1 = pb1[h * Cc + c], w2 = pw2[h * Cc + c];
            float h0 = fmaf(w1, d0, b1), h1 = fmaf(w1, d1, b1);
            y0 = fmaf(w2, h0 >= 0.f ? h0 : 0.01f * h0, y0);
            y1 = fmaf(w2, h1 >= 0.f ? h1 : 0.01f * h1, y1);
        }
        float a = (y1 - y0) * (float)LUTN;
        LUT[bin * Hc + h] = make_float2(a, y0 - a * d0);
    }
}

// ---------------- K1: QKV fused fp32 GEMM -> bf16 Q,K (l2norm) + V^T --------
#define BM 64
#define BN 64
#define BK 64
#define LS 68

__global__ __launch_bounds__(256) void gemm_qkv(
    const float* __restrict__ x,
    const float* __restrict__ Wq, const float* __restrict__ Wk,
    const float* __restrict__ Wv,
    ushort* __restrict__ Qb, ushort* __restrict__ Kb, ushort* __restrict__ Vt)
{
    const int tid = threadIdx.x;
    const int tr = tid >> 4;
    const int tc = tid & 15;
    const int rbase = blockIdx.x * BM;
    const int ft = blockIdx.y;
    const int mat = ft >> 2;
    const int fb = (ft & 3) * BN;

    const float* Wsel = (mat == 0) ? Wq : (mat == 1) ? Wk : Wv;

    __shared__ __align__(16) float As[BK][LS];
    __shared__ __align__(16) float Ws[BK][LS];

    float acc[4][4];
#pragma unroll
    for (int i = 0; i < 4; ++i)
#pragma unroll
        for (int j = 0; j < 4; ++j) acc[i][j] = 0.f;

    const int lr = tid >> 2;
    const int lk = (tid & 3) << 4;

    for (int k0 = 0; k0 < Dc; k0 += BK) {
        const float* ag = x + (size_t)(rbase + lr) * Dc + k0 + lk;
        const float* wg = Wsel + (size_t)(fb + lr) * Dc + k0 + lk;
#pragma unroll
        for (int j = 0; j < 4; ++j) {
            float4 a4 = *(const float4*)(ag + 4 * j);
            float4 w4 = *(const float4*)(wg + 4 * j);
            const int kk = lk + 4 * j;
            As[kk + 0][lr] = a4.x; As[kk + 1][lr] = a4.y;
            As[kk + 2][lr] = a4.z; As[kk + 3][lr] = a4.w;
            Ws[kk + 0][lr] = w4.x; Ws[kk + 1][lr] = w4.y;
            Ws[kk + 2][lr] = w4.z; Ws[kk + 3][lr] = w4.w;
        }
        __syncthreads();
#pragma unroll 4
        for (int k = 0; k < BK; ++k) {
            float4 a4 = *(const float4*)&As[k][tr * 4];
            float4 w4 = *(const float4*)&Ws[k][tc * 4];
            acc[0][0] = fmaf(a4.x, w4.x, acc[0][0]);
            acc[0][1] = fmaf(a4.x, w4.y, acc[0][1]);
            acc[0][2] = fmaf(a4.x, w4.z, acc[0][2]);
            acc[0][3] = fmaf(a4.x, w4.w, acc[0][3]);
            acc[1][0] = fmaf(a4.y, w4.x, acc[1][0]);
            acc[1][1] = fmaf(a4.y, w4.y, acc[1][1]);
            acc[1][2] = fmaf(a4.y, w4.z, acc[1][2]);
            acc[1][3] = fmaf(a4.y, w4.w, acc[1][3]);
            acc[2][0] = fmaf(a4.z, w4.x, acc[2][0]);
            acc[2][1] = fmaf(a4.z, w4.y, acc[2][1]);
            acc[2][2] = fmaf(a4.z, w4.z, acc[2][2]);
            acc[2][3] = fmaf(a4.z, w4.w, acc[2][3]);
            acc[3][0] = fmaf(a4.w, w4.x, acc[3][0]);
            acc[3][1] = fmaf(a4.w, w4.y, acc[3][1]);
            acc[3][2] = fmaf(a4.w, w4.z, acc[3][2]);
            acc[3][3] = fmaf(a4.w, w4.w, acc[3][3]);
        }
        __syncthreads();
    }

    const int flocal = fb + tc * 4;
    if (mat < 2) {
        ushort* Out = (mat == 0) ? Qb : Kb;
        const int h = flocal >> 5;
        const int dk = flocal & 31;
#pragma unroll
        for (int i = 0; i < 4; ++i) {
            float ss = acc[i][0] * acc[i][0] + acc[i][1] * acc[i][1]
                     + acc[i][2] * acc[i][2] + acc[i][3] * acc[i][3];
            ss += __shfl_xor(ss, 1, 64);
            ss += __shfl_xor(ss, 2, 64);
            ss += __shfl_xor(ss, 4, 64);
            float scn = 1.f / fmaxf(sqrtf(ss), 1e-12f);
            const int row = rbase + tr * 4 + i;
            const int bb = row >> 10, tt = row & 1023;
            uint2 pkd;
            pkd.x = pk2(acc[i][0] * scn, acc[i][1] * scn);
            pkd.y = pk2(acc[i][2] * scn, acc[i][3] * scn);
            *(uint2*)(Out + (((size_t)(bb * 8 + h) * Tc + tt) * 32 + dk)) = pkd;
        }
    } else {
        const int row = rbase + tr * 4;       // 4 consecutive t, same b
        const int bb = row >> 10, tt = row & 1023;
#pragma unroll
        for (int j = 0; j < 4; ++j) {
            const int f = flocal + j;
            const int h = f >> 5, vl = f & 31;
            uint2 pkd;
            pkd.x = pk2(acc[0][j], acc[1][j]);
            pkd.y = pk2(acc[2][j], acc[3][j]);
            *(uint2*)(Vt + ((size_t)(bb * 8 + h) * 32 + vl) * Tc + tt) = pkd;
        }
    }
}

// ---------------- K2: MFMA flash attention ---------------------------------
// grid (T/16, B, 2). block 256 = 4 waves = 4 s-quarters.
// wave: 16 t-rows x 4 heads x 256 s. No barriers in the s-loop.
__global__ __launch_bounds__(256) void attn_mfma(
    const ushort* __restrict__ Qb, const ushort* __restrict__ Kb,
    const ushort* __restrict__ Vt,
    const float* __restrict__ rel, const int* __restrict__ msk,
    const float2* __restrict__ LUT,
    float* __restrict__ Y)
{
    const int tid = threadIdx.x;
    const int w = tid >> 6;
    const int l = tid & 63;
    const int u = l & 15;
    const int g = l >> 4;
    const int t0 = blockIdx.x * 16;
    const int b = blockIdx.y;
    const int hg = blockIdx.z;

    __shared__ __align__(16) float lut_s[LUTN * 8];   // [bin][4 heads](a,b)
    __shared__ __align__(16) unsigned plds[4 * 320];  // per-wave P scratch (16 x 80B)
    __shared__ __align__(16) float comb[4 * 2112];    // [w][16 t][132]
    __shared__ float rs_s[4 * 4 * 16];                // [w][hi][t]

    // stage this head-group's LUT: 4 heads -> 8 floats per bin
    {
        const float4* src = (const float4*)(LUT + (size_t)tid * Hc + hg * 4);
        float4* dst = (float4*)(lut_s + tid * 8);
        dst[0] = src[0];
        dst[1] = src[1];
    }

    const int bh0 = b * 8 + hg * 4;
    short8 qf[4];
#pragma unroll
    for (int hi = 0; hi < 4; ++hi)
        qf[hi] = *(const short8*)(Qb + (((size_t)(bh0 + hi) * Tc + t0 + u) * 32 + g * 8));

    f32x4 oacc[4][2];
#pragma unroll
    for (int hi = 0; hi < 4; ++hi)
#pragma unroll
        for (int vt = 0; vt < 2; ++vt)
            oacc[hi][vt] = (f32x4){0.f, 0.f, 0.f, 0.f};
    float rs[4][4];
#pragma unroll
    for (int hi = 0; hi < 4; ++hi)
#pragma unroll
        for (int reg = 0; reg < 4; ++reg) rs[hi][reg] = 0.f;

    unsigned* pwb = plds + w * 320;
    const float4* lutv = (const float4*)lut_s;
    const size_t dbase = (size_t)b * Tc * Tc;

    __syncthreads();   // LUT staged

    const int s_begin = w * 256;
    for (int sc = s_begin; sc < s_begin + 256; sc += 32) {
        // d / mask with sentinel (d >= 0 for live entries)
        float dA[4], dB[4];
#pragma unroll
        for (int reg = 0; reg < 4; ++reg) {
            const int t = t0 + 4 * g + reg;
            const size_t off = dbase + (size_t)t * Tc + sc + 2 * u;
            float2 d2 = *(const float2*)(rel + off);
            int2 m2 = *(const int2*)(msk + off);
            dA[reg] = m2.x ? -1.f : d2.x;
            dB[reg] = m2.y ? -1.f : d2.y;
        }
        // bias = a*d + b, per (reg, head); bins shared across heads
        float biasA[4][4], biasB[4][4];
#pragma unroll
        for (int reg = 0; reg < 4; ++reg) {
            int iA = (int)(dA[reg] * (float)LUTN);
            int iB = (int)(dB[reg] * (float)LUTN);
            iA = iA < 0 ? 0 : (iA > LUTN - 1 ? LUTN - 1 : iA);
            iB = iB < 0 ? 0 : (iB > LUTN - 1 ? LUTN - 1 : iB);
            float4 a0 = lutv[iA * 2], a1 = lutv[iA * 2 + 1];
            float4 b0 = lutv[iB * 2], b1 = lutv[iB * 2 + 1];
            biasA[reg][0] = fmaf(a0.x, dA[reg], a0.y);
            biasA[reg][1] = fmaf(a0.z, dA[reg], a0.w);
            biasA[reg][2] = fmaf(a1.x, dA[reg], a1.y);
            biasA[reg][3] = fmaf(a1.z, dA[reg], a1.w);
            biasB[reg][0] = fmaf(b0.x, dB[reg], b0.y);
            biasB[reg][1] = fmaf(b0.z, dB[reg], b0.w);
            biasB[reg][2] = fmaf(b1.x, dB[reg], b1.y);
            biasB[reg][3] = fmaf(b1.z, dB[reg], b1.w);
        }
#pragma unroll
        for (int hi = 0; hi < 4; ++hi) {
            // K B-frags straight from global/L2: tileA = even s, tileB = odd s
            const size_t kb = ((size_t)(bh0 + hi) * Tc + sc + 2 * u) * 32 + g * 8;
            short8 kfA = *(const short8*)(Kb + kb);
            short8 kfB = *(const short8*)(Kb + kb + 32);
            const f32x4 z4 = (f32x4){0.f, 0.f, 0.f, 0.f};
            f32x4 sA = __builtin_amdgcn_mfma_f32_16x16x32_bf16(qf[hi], kfA, z4, 0, 0, 0);
            f32x4 sB = __builtin_amdgcn_mfma_f32_16x16x32_bf16(qf[hi], kfB, z4, 0, 0, 0);
#pragma unroll
            for (int reg = 0; reg < 4; ++reg) {
                float zA = (dA[reg] < 0.f) ? 0.f : __expf(sA[reg] - biasA[reg][hi]);
                float zB = (dB[reg] < 0.f) ? 0.f : __expf(sB[reg] - biasB[reg][hi]);
                rs[hi][reg] += zA + zB;
                pwb[(4 * g + reg) * 20 + u] = pk2(zA, zB);  // P[t][2u],(2u+1)
            }
            // P C-layout -> A-layout via per-wave LDS round trip
            short8 pf = *(const short8*)((const char*)pwb + u * 80 + g * 16);
            const size_t vb = ((size_t)(bh0 + hi) * 32 + u) * Tc + sc + g * 8;
            short8 vf0 = *(const short8*)(Vt + vb);
            short8 vf1 = *(const short8*)(Vt + vb + (size_t)16 * Tc);
            oacc[hi][0] = __builtin_amdgcn_mfma_f32_16x16x32_bf16(pf, vf0, oacc[hi][0], 0, 0, 0);
            oacc[hi][1] = __builtin_amdgcn_mfma_f32_16x16x32_bf16(pf, vf1, oacc[hi][1], 0, 0, 0);
        }
    }

    // row-sum reduce across the 16 s-lanes, stash per wave
#pragma unroll
    for (int hi = 0; hi < 4; ++hi)
#pragma unroll
        for (int reg = 0; reg < 4; ++reg) {
            float v = rs[hi][reg];
            v += __shfl_xor(v, 1, 64);
            v += __shfl_xor(v, 2, 64);
            v += __shfl_xor(v, 4, 64);
            v += __shfl_xor(v, 8, 64);
            if (u == 0) rs_s[(w * 4 + hi) * 16 + 4 * g + reg] = v;
        }
    // O partials to comb
#pragma unroll
    for (int hi = 0; hi < 4; ++hi)
#pragma unroll
        for (int vt = 0; vt < 2; ++vt)
#pragma unroll
            for (int reg = 0; reg < 4; ++reg)
                comb[w * 2112 + (4 * g + reg) * 132 + hi * 32 + vt * 16 + u] =
                    oacc[hi][vt][reg];
    __syncthreads();

    // combine 4 s-quarters, normalize, store
    const int tl = tid >> 4;
    const int f0 = (tid & 15) * 8;
    const int hl = f0 >> 5;
    float rstot = rs_s[(0 + hl) * 16 + tl] + rs_s[(4 + hl) * 16 + tl]
                + rs_s[(8 + hl) * 16 + tl] + rs_s[(12 + hl) * 16 + tl];
    float inv = 1.f / (rstot + 1e-5f);
    float o[8];
#pragma unroll
    for (int k = 0; k < 8; ++k) o[k] = 0.f;
#pragma unroll
    for (int ww = 0; ww < 4; ++ww) {
        const float4* p = (const float4*)(comb + ww * 2112 + tl * 132 + f0);
        float4 a = p[0], bq = p[1];
        o[0] += a.x; o[1] += a.y; o[2] += a.z; o[3] += a.w;
        o[4] += bq.x; o[5] += bq.y; o[6] += bq.z; o[7] += bq.w;
    }
    float* yp = Y + ((size_t)b * Tc + t0 + tl) * Dc + hg * 128 + f0;
    float4 w0, w1;
    w0.x = o[0] * inv; w0.y = o[1] * inv; w0.z = o[2] * inv; w0.w = o[3] * inv;
    w1.x = o[4] * inv; w1.y = o[5] * inv; w1.z = o[6] * inv; w1.w = o[7] * inv;
    *(float4*)yp = w0;
    *(float4*)(yp + 4) = w1;
}

// ---------------- K3/K5: GEMM + bias (+lrelu) ------------------------------
__global__ __launch_bounds__(256) void gemm_bias(
    const float* __restrict__ A, const float* __restrict__ W,
    const float* __restrict__ bias, float* __restrict__ out, int do_lrelu)
{
    const int tid = threadIdx.x;
    const int tr = tid >> 4;
    const int tc = tid & 15;
    const int rbase = blockIdx.x * BM;
    const int fb = blockIdx.y * BN;

    __shared__ __align__(16) float As[BK][LS];
    __shared__ __align__(16) float Ws[BK][LS];

    float acc[4][4];
#pragma unroll
    for (int i = 0; i < 4; ++i)
#pragma unroll
        for (int j = 0; j < 4; ++j) acc[i][j] = 0.f;

    const int lr = tid >> 2;
    const int lk = (tid & 3) << 4;

    for (int k0 = 0; k0 < Dc; k0 += BK) {
        const float* ag = A + (size_t)(rbase + lr) * Dc + k0 + lk;
        const float* wg = W + (size_t)(fb + lr) * Dc + k0 + lk;
#pragma unroll
        for (int j = 0; j < 4; ++j) {
            float4 a4 = *(const float4*)(ag + 4 * j);
            float4 w4 = *(const float4*)(wg + 4 * j);
            const int kk = lk + 4 * j;
            As[kk + 0][lr] = a4.x; As[kk + 1][lr] = a4.y;
            As[kk + 2][lr] = a4.z; As[kk + 3][lr] = a4.w;
            Ws[kk + 0][lr] = w4.x; Ws[kk + 1][lr] = w4.y;
            Ws[kk + 2][lr] = w4.z; Ws[kk + 3][lr] = w4.w;
        }
        __syncthreads();
#pragma unroll 4
        for (int k = 0; k < BK; ++k) {
            float4 a4 = *(const float4*)&As[k][tr * 4];
            float4 w4 = *(const float4*)&Ws[k][tc * 4];
            acc[0][0] = fmaf(a4.x, w4.x, acc[0][0]);
            acc[0][1] = fmaf(a4.x, w4.y, acc[0][1]);
            acc[0][2] = fmaf(a4.x, w4.z, acc[0][2]);
            acc[0][3] = fmaf(a4.x, w4.w, acc[0][3]);
            acc[1][0] = fmaf(a4.y, w4.x, acc[1][0]);
            acc[1][1] = fmaf(a4.y, w4.y, acc[1][1]);
            acc[1][2] = fmaf(a4.y, w4.z, acc[1][2]);
            acc[1][3] = fmaf(a4.y, w4.w, acc[1][3]);
            acc[2][0] = fmaf(a4.z, w4.x, acc[2][0]);
            acc[2][1] = fmaf(a4.z, w4.y, acc[2][1]);
            acc[2][2] = fmaf(a4.z, w4.z, acc[2][2]);
            acc[2][3] = fmaf(a4.z, w4.w, acc[2][3]);
            acc[3][0] = fmaf(a4.w, w4.x, acc[3][0]);
            acc[3][1] = fmaf(a4.w, w4.y, acc[3][1]);
            acc[3][2] = fmaf(a4.w, w4.z, acc[3][2]);
            acc[3][3] = fmaf(a4.w, w4.w, acc[3][3]);
        }
        __syncthreads();
    }

    const int fcol = fb + tc * 4;
    float4 bv = *(const float4*)(bias + fcol);
#pragma unroll
    for (int i = 0; i < 4; ++i) {
        const int row = rbase + tr * 4 + i;
        float4 o;
        o.x = acc[i][0] + bv.x; o.y = acc[i][1] + bv.y;
        o.z = acc[i][2] + bv.z; o.w = acc[i][3] + bv.w;
        if (do_lrelu) {
            o.x = o.x >= 0.f ? o.x : 0.01f * o.x;
            o.y = o.y >= 0.f ? o.y : 0.01f * o.y;
            o.z = o.z >= 0.f ? o.z : 0.01f * o.z;
            o.w = o.w >= 0.f ? o.w : 0.01f * o.w;
        }
        *(float4*)(out + (size_t)row * Dc + fcol) = o;
    }
}

// ---------------- K4/K6: residual + LayerNorm ------------------------------
__global__ __launch_bounds__(256) void resid_ln_kernel(
    const float* __restrict__ y, const float* __restrict__ res,
    const float* __restrict__ g, const float* __restrict__ beta,
    float* __restrict__ out)
{
    const int j = threadIdx.x;
    const int row = blockIdx.x;
    __shared__ float red[8];
    float s = y[(size_t)row * Dc + j] + res[(size_t)row * Dc + j];

    float s1 = s, s2 = s * s;
#pragma unroll
    for (int m = 32; m >= 1; m >>= 1) {
        s1 += __shfl_xor(s1, m, 64);
        s2 += __shfl_xor(s2, m, 64);
    }
    const int w = j >> 6;
    if ((j & 63) == 0) { red[w] = s1; red[w + 4] = s2; }
    __syncthreads();
    float S1 = red[0] + red[1] + red[2] + red[3];
    float S2 = red[4] + red[5] + red[6] + red[7];
    float mu = S1 * (1.f / Dc);
    float var = S2 * (1.f / Dc) - mu * mu;
    float o = (s - mu) * rsqrtf(var + 1e-5f) * g[j] + beta[j];
    out[(size_t)row * Dc + j] = o;
}

extern "C" void kernel_launch(void* const* d_in, const int* in_sizes, int n_in,
                              void* d_out, int out_size, void* d_ws, size_t ws_size,
                              hipStream_t stream) {
    const float* x    = (const float*)d_in[0];
    const int*   mask = (const int*)d_in[1];
    const float* rel  = (const float*)d_in[2];
    const float* Wq   = (const float*)d_in[3];
    const float* Wk   = (const float*)d_in[4];
    const float* Wv   = (const float*)d_in[5];
    const float* pw1  = (const float*)d_in[6];
    const float* pb1  = (const float*)d_in[7];
    const float* pw2  = (const float*)d_in[8];
    const float* pb2  = (const float*)d_in[9];
    const float* Wo   = (const float*)d_in[10];
    const float* bo   = (const float*)d_in[11];
    const float* Wf   = (const float*)d_in[12];
    const float* bf   = (const float*)d_in[13];
    const float* g1   = (const float*)d_in[14];
    const float* be1  = (const float*)d_in[15];
    const float* g2   = (const float*)d_in[16];
    const float* be2  = (const float*)d_in[17];
    float* out = (float*)d_out;

    char* wsb = (char*)d_ws;
    ushort* Qb = (ushort*)(wsb);                       // 2 MB bf16 [bh][t][32]
    ushort* Kb = (ushort*)(wsb + (size_t)(2 << 20));   // 2 MB
    ushort* Vt = (ushort*)(wsb + (size_t)(4 << 20));   // 2 MB bf16 [bh][32][t]
    float*  Y  = (float*)(wsb + (size_t)(6 << 20));    // 4 MB
    float*  PY = (float*)(wsb + (size_t)(10 << 20));   // 4 MB
    float*  ZZ = (float*)(wsb + (size_t)(14 << 20));   // 4 MB
    float*  FY = (float*)(wsb + (size_t)(18 << 20));   // 4 MB
    float2* LUT = (float2*)(wsb + (size_t)(22 << 20)); // 16 KB

    lut_build<<<1, 256, 0, stream>>>(pw1, pb1, pw2, pb2, LUT);
    gemm_qkv<<<dim3(Bc * Tc / BM, 12), 256, 0, stream>>>(x, Wq, Wk, Wv, Qb, Kb, Vt);
    attn_mfma<<<dim3(Tc / 16, Bc, 2), 256, 0, stream>>>(Qb, Kb, Vt, rel, mask, LUT, Y);
    gemm_bias<<<dim3(Bc * Tc / BM, Dc / BN), 256, 0, stream>>>(Y, Wo, bo, PY, 0);
    resid_ln_kernel<<<Bc * Tc, Dc, 0, stream>>>(PY, x, g1, be1, ZZ);
    gemm_bias<<<dim3(Bc * Tc / BM, Dc / BN), 256, 0, stream>>>(ZZ, Wf, bf, FY, 1);
    resid_ln_kernel<<<Bc * Tc, Dc, 0, stream>>>(FY, ZZ, g2, be2, out);
}